// Round 9
// baseline (260.675 us; speedup 1.0000x reference)
//
#include <hip/hip_runtime.h>
#include <math.h>

#define N 4096
#define ROUNDS 12           // round 0 (folded) + 11: components at least halve per hook
#define INFKEY 0xFFFFFFFFFFFFFFFFULL
#define LCAP 64             // candidate-list capacity per row == wave width
#define EC (N - 1)          // MST edge count
#define M2 (2 * EC)         // directed edges (8190)
#define MBLK 64             // blocks per matrix (128 total; viable with 1 hierarchical barrier/round)
#define GSZ 8               // blocks per barrier group
#define NG (MBLK / GSZ)     // 8 groups per matrix
#define RPB (N / MBLK)      // 64 rows per block
#define RPW (RPB / 16)      // 4 rows per wave

typedef unsigned long long u64;
typedef unsigned int u32;
typedef unsigned short u16;
typedef unsigned char u8;

// ---- workspace layout (bytes) ----
#define WS_PARENT(ws) ((int*)((char*)(ws) + 0))          // int[2N]        32 KB
#define WS_RCNT(ws)   ((int*)((char*)(ws) + 32768))      // int[2N]        32 KB
#define WS_RTHR(ws)   ((float*)((char*)(ws) + 65536))    // float[2N]      32 KB
#define WS_EDGES(ws)  ((int2*)((char*)(ws) + 98304))     // int2[2N]       64 KB
#define WS_CAND(ws)   ((u64*)((char*)(ws) + 163840))     // u64[2][2N]    128 KB (double-buffered)
#define WS_META(ws)   ((int*)((char*)(ws) + 294912))     // int[64]
#define WS_LISTS(ws)  ((u64*)((char*)(ws) + 295168))     // u64[2N*LCAP]    4 MB, row-major

// cand key (TAGGED): ((ROUNDS-round) << 56) | (float_bits(w) << 24) | (u << 12) | v
//   Tags strictly decrease per round -> fresh keys always win atomicMin vs
//   stale same-buffer keys; phase C validates tag instead of INFKEY, so no
//   per-round buffer reset and only ONE mat_barrier per round.
// list entry: (float_bits(w) << 12) | j  (44 bits); order irrelevant.
// meta layout: matrix m uses meta[m*16+0..7] = group arrival counters
//   (monotonic), meta[m*16+8] = global arrival counter (monotonic),
//   meta[m*16+9] = generation. meta[40] = final arrive counter (all blocks).

// Two-level monotonic spin barrier over MBLK blocks. Group g = bm & 7 -> the
// 8 same-(b&7) blocks share an XCD under the usual round-robin mapping, so
// group arrivals are XCD-local L2 atomics (correct either way); only the 8
// group leaders touch the cross-XCD global counter. R2 showed flat 128-wide
// arrivals cost ~3.7 us/barrier; this caps the cross-XCD fan-in at 8.
__device__ __forceinline__ void mat_barrier(int* mbase, int bm, int target) {
    __syncthreads();
    if (threadIdx.x == 0) {
        __threadfence();
        const int g = bm & (NG - 1);
        int old = atomicAdd(&mbase[g], 1);            // group arrival (monotonic)
        bool released = false;
        if (old == target * GSZ - 1) {                // group leader this barrier
            int o2 = atomicAdd(&mbase[8], 1);         // global arrival
            if (o2 == target * NG - 1) {
                __hip_atomic_store(&mbase[9], target, __ATOMIC_RELEASE, __HIP_MEMORY_SCOPE_AGENT);
                released = true;
            }
        }
        if (!released) {
            while (__hip_atomic_load(&mbase[9], __ATOMIC_ACQUIRE, __HIP_MEMORY_SCOPE_AGENT) < target)
                __builtin_amdgcn_s_sleep(1);
        }
        __threadfence();
    }
    __syncthreads();
}

// One 256-thread BLOCK per row (grid 8192). sigma-based one-shot ball
// threshold: T = mean - 2.25*sigma targets ~50 entries (retry-halving if >64,
// P~2-3%); emission via LDS atomic counter (order irrelevant). Verified in
// round 8: cut solve's phase-B rescans, solve 155 -> 116 us.
__global__ __launch_bounds__(256) void build_kernel(const float* __restrict__ D1,
                                                    const float* __restrict__ D2,
                                                    int* __restrict__ rowcount,
                                                    float* __restrict__ rthresh,
                                                    u64* __restrict__ lists,
                                                    u64* __restrict__ cand,
                                                    int* __restrict__ meta) {
    const int gb = blockIdx.x;   // 8192 blocks: one per (matrix,row)
    const int tid = threadIdx.x;
    const int wid = tid >> 6, lane = tid & 63;

    // folded init: cand buffer 1 (buffer 0 is fully written below) + meta
    if (gb < 8) {
        int i = 2 * N + (gb * 256 + tid) * 4;
        cand[i] = INFKEY; cand[i + 1] = INFKEY; cand[i + 2] = INFKEY; cand[i + 3] = INFKEY;
    } else if (gb == 8 && tid < 64) {
        meta[tid] = 0;
    }

    const int m = gb >> 12;
    const int row = gb & (N - 1);
    const float* __restrict__ Drow = (m ? D2 : D1) + (size_t)row * N;

    __shared__ u64 skmin[4];
    __shared__ float ssum[4];
    __shared__ float ssq[4];
    __shared__ int semit;

    float4 v[4];
#pragma unroll
    for (int it = 0; it < 4; ++it)
        v[it] = *(const float4*)(Drow + it * 1024 + tid * 4);

    // pass 1: per-thread min KEY + sum over 16 elems
    u64 kmin = INFKEY;
    float sm = 0.f;
#pragma unroll
    for (int it = 0; it < 4; ++it) {
        float e4[4] = {v[it].x, v[it].y, v[it].z, v[it].w};
#pragma unroll
        for (int s = 0; s < 4; ++s) {
            float x = e4[s];
            if (x > 0.f) {   // excludes exact-zero diagonal
                u64 k = ((u64)__float_as_uint(x) << 12) | (unsigned)(it * 1024 + tid * 4 + s);
                if (k < kmin) kmin = k;
            }
            sm += x;         // self adds 0, harmless
        }
    }
#pragma unroll
    for (int off = 32; off > 0; off >>= 1) {
        u64 o = __shfl_xor(kmin, off, 64);
        if (o < kmin) kmin = o;
        sm += __shfl_xor(sm, off, 64);
    }
    if (lane == 0) { skmin[wid] = kmin; ssum[wid] = sm; }
    __syncthreads();
    kmin = skmin[0]; sm = ssum[0];
#pragma unroll
    for (int w = 1; w < 4; ++w) {
        if (skmin[w] < kmin) kmin = skmin[w];
        sm += ssum[w];
    }
    const float mn = __uint_as_float((u32)(kmin >> 12));
    const float mean = sm * (1.f / 4095.f);

    // pass 2 (registers): sum of squared deviations -> sigma
    float sq = 0.f;
#pragma unroll
    for (int it = 0; it < 4; ++it) {
        float e4[4] = {v[it].x, v[it].y, v[it].z, v[it].w};
#pragma unroll
        for (int s = 0; s < 4; ++s) {
            float x = e4[s];
            if (x > 0.f) { float d = x - mean; sq += d * d; }
        }
    }
#pragma unroll
    for (int off = 32; off > 0; off >>= 1) sq += __shfl_xor(sq, off, 64);
    if (lane == 0) ssq[wid] = sq;
    __syncthreads();
    sq = ssq[0] + ssq[1] + ssq[2] + ssq[3];
    const float sigma = sqrtf(fmaxf(sq * (1.f / 4095.f), 0.f));

    const float gap = mean - mn;
    float T = mean - 2.25f * sigma;          // ~1.2% quantile ~= 50 entries
    const float Tlo = mn + 0.001f * gap;     // guarantee at least the row min
    if (!(T > Tlo)) T = Tlo;                 // also catches NaN

    // emit-with-count loop: atomic positions, retry-halve on overflow (rare)
    u64* lp = lists + ((size_t)m * N + row) * LCAP;   // ROW-major
    int total = 0;
    for (int tries = 0; tries < 8; ++tries) {
        __syncthreads();
        if (tid == 0) semit = 0;
        __syncthreads();
#pragma unroll
        for (int it = 0; it < 4; ++it) {
            float e4[4] = {v[it].x, v[it].y, v[it].z, v[it].w};
#pragma unroll
            for (int s = 0; s < 4; ++s) {
                float x = e4[s];
                if (x > 0.f && x < T) {
                    int p = atomicAdd(&semit, 1);
                    if (p < LCAP)
                        lp[p] = ((u64)__float_as_uint(x) << 12) | (unsigned)(it * 1024 + tid * 4 + s);
                }
            }
        }
        __syncthreads();
        total = semit;                        // block-uniform
        if (total <= LCAP) break;             // uniform break
        T = mn + 0.5f * (T - mn);
    }

    if (tid == 0) {
        rowcount[m * N + row] = total;
        rthresh[m * N + row] = T;
        // Boruvka round-0 candidate, tag = ROUNDS, unique writer per row
        cand[m * N + row] = ((u64)ROUNDS << 56) | ((kmin >> 12) << 24) | ((u64)row << 12) | (kmin & 0xFFF);
    }
}

// 64 blocks per matrix (128 total). Round 0 = hook only. Rounds 1+:
// A (list scan + flush) -> B (bound filter + rare rescans) -> hierarchical
// mat_barrier -> C (redundant deterministic hook+compress). MBLK=64 halves
// phase A's serial chains and spreads B's rescan stragglers over 2x blocks;
// the 2-level barrier caps cross-XCD arrival fan-in at 8 (R2's flat 128-wide
// barrier cost ~3.7us/crossing).
__global__ __launch_bounds__(1024) void solve_kernel(const float* __restrict__ D1,
                                                     const float* __restrict__ D2,
                                                     const int* __restrict__ rcnt,
                                                     const float* __restrict__ rthr,
                                                     const u64* __restrict__ lists,
                                                     u64* __restrict__ cand_g,
                                                     int2* __restrict__ edges_g,
                                                     int* __restrict__ parent_g,
                                                     int* __restrict__ meta,
                                                     float* __restrict__ out) {
    const int b = blockIdx.x;
    const int m = b / MBLK;
    const int bm = b - m * MBLK;
    const int tid = threadIdx.x;
    const int wid = tid >> 6, lane = tid & 63;
    const float* __restrict__ D = m ? D2 : D1;
    const int* __restrict__ grc = rcnt + m * N;
    const float* __restrict__ gth = rthr + m * N;
    const u64* __restrict__ gls = lists + (size_t)m * N * LCAP;
    int2* __restrict__ ged = edges_g + (size_t)m * N;
    int* __restrict__ gpar = parent_g + m * N;
    int* mbase = meta + m * 16;            // group counters [0..7], global [8], gen [9]
    int* garr = meta + 40;                 // global arrive counter (all 128 blocks)
    const float INF = __builtin_inff();

    __shared__ __align__(16) char SM[57344];   // 56 KB arena, phase-aliased
    u16* comp0 = (u16*)SM;                     // 8 KB @0    (component buffer A)
    u16* comp1 = (u16*)(SM + 8192);            // 8 KB @8K   (component buffer B)
    u64* scand = (u64*)(SM + 16384);           // 32 KB @16K (local min mirror / staged cand)
    u16* sresc = (u16*)(SM + 49152);           // 8 KB  @48K (rescan list)
    __shared__ u8 sexh[RPB];                   // monotone exhausted-row flags
    __shared__ int snres, secnt, sdone[ROUNDS], swar[16];

    u16* cur = comp0;                          // swapped identically in all threads
    u16* nxt = comp1;

    for (int i = tid; i < N; i += 1024) cur[i] = (u16)i;
    for (int i = tid; i < RPB; i += 1024) sexh[i] = 0;
    if (tid == 0) secnt = 0;
    if (tid < ROUNDS) sdone[tid] = 0;
    int phase = 0;
    bool done = false;

    for (int round = 0; round < ROUNDS && !done; ++round) {
        const int buf = round & 1;
        const u64 tg = (u64)(ROUNDS - round);          // this round's tag
        const u64 tgs = tg << 56;
        u64* __restrict__ gcand = cand_g + (size_t)buf * 2 * N + m * N;

        if (round > 0) {
            for (int i = tid; i < N; i += 1024) scand[i] = INFKEY;
            if (tid == 0) snres = 0;
            __syncthreads();

            // ---- phase A: prefetched list scan; exhausted rows skip ----
            {
                const int lbase = wid * RPW;
                int cnts[RPW];
                u64 ent[RPW];
#pragma unroll
                for (int r = 0; r < RPW; ++r) {
                    int lrow = lbase + r;
                    cnts[r] = sexh[lrow] ? -1 : grc[bm * RPB + lrow];   // uniform scalar load
                }
#pragma unroll
                for (int r = 0; r < RPW; ++r) {   // independent global loads in flight
                    int lrow = lbase + r;
                    ent[r] = (cnts[r] > lane) ? gls[(size_t)(bm * RPB + lrow) * LCAP + lane]
                                              : INFKEY;
                }
#pragma unroll
                for (int r = 0; r < RPW; ++r) {
                    const int lrow = lbase + r;
                    const int row = bm * RPB + lrow;
                    if (cnts[r] < 0) {                       // known exhausted
                        if (lane == 0) { int i = atomicAdd(&snres, 1); sresc[i] = (u16)(row | 0x1000); }
                        continue;
                    }
                    if (cnts[r] > LCAP) {                    // defensive overflow
                        if (lane == 0) { int i = atomicAdd(&snres, 1); sresc[i] = (u16)(row | 0x4000); }
                        continue;
                    }
                    const int c = cur[row];
                    u64 e = ent[r];
                    u64 best = (e != INFKEY && cur[(int)(e & 0xFFF)] != c) ? e : INFKEY;
#pragma unroll
                    for (int off = 32; off > 0; off >>= 1) {
                        u64 o = __shfl_xor(best, off, 64);
                        if (o < best) best = o;
                    }
                    if (lane == 0) {
                        if (best != INFKEY) {
                            u64 key = tgs | ((best >> 12) << 24) | ((u64)row << 12) | (best & 0xFFF);
                            if (key < scand[c]) atomicMin(&scand[c], key);
                        } else {
                            sexh[lrow] = 1;                  // permanent (monotone)
                            int i = atomicAdd(&snres, 1); sresc[i] = (u16)(row | 0x1000);
                        }
                    }
                }
            }
            __syncthreads();
            for (int c = tid; c < N; c += 1024) {            // flush block-local mins
                u64 v = scand[c];
                if (v != INFKEY) atomicMin(&gcand[c], v);
            }
            __syncthreads();                 // own flushes visible to own filter reads

            // ---- phase B (no preceding barrier): bound filter; rare rescans ----
            for (int i = tid; i < snres; i += 1024) {
                u16 e = sresc[i];
                if (e & 0x1000) {
                    int row = e & 0xFFF;
                    int c = cur[row];
                    u64 cc = gcand[c];           // partial/monotone: skip stays safe
                    float w = ((cc >> 56) == tg) ? __uint_as_float((u32)(cc >> 24)) : INF;
                    if (!(gth[row] < w)) sresc[i] = 0xFFFF;
                }
            }
            __syncthreads();
            {
                const int nres = snres;
                for (int i = wid; i < nres; i += 16) {
                    u16 e = sresc[i];            // wave-uniform broadcast
                    if (e == 0xFFFF) continue;
                    int row = (int)(e & 0xFFF);
                    int c = cur[row];
                    const float* Drow = D + (size_t)row * N;
                    u64 best = INFKEY;
                    for (int j0 = lane * 4; j0 < N; j0 += 256) {
                        float4 d = *(const float4*)(Drow + j0);
                        ushort4 cj = *(const ushort4*)(cur + j0);
                        if (cj.x != c) { u64 k = ((u64)__float_as_uint(d.x) << 12) | (unsigned)(j0 + 0); if (k < best) best = k; }
                        if (cj.y != c) { u64 k = ((u64)__float_as_uint(d.y) << 12) | (unsigned)(j0 + 1); if (k < best) best = k; }
                        if (cj.z != c) { u64 k = ((u64)__float_as_uint(d.z) << 12) | (unsigned)(j0 + 2); if (k < best) best = k; }
                        if (cj.w != c) { u64 k = ((u64)__float_as_uint(d.w) << 12) | (unsigned)(j0 + 3); if (k < best) best = k; }
                    }
#pragma unroll
                    for (int off = 32; off > 0; off >>= 1) {
                        u64 o = __shfl_xor(best, off, 64);
                        if (o < best) best = o;
                    }
                    if (lane == 0 && best != INFKEY) {
                        u64 key = tgs | ((best >> 12) << 24) | ((u64)row << 12) | (best & 0xFFF);
                        atomicMin(&gcand[c], key);
                    }
                }
            }
            mat_barrier(mbase, bm, ++phase);   // the single per-round barrier
        }

        // ---- phase C (all blocks, redundant+deterministic): stage cand (tag-
        //      validated), hook into nxt, walk+count fused, swap buffers ----
        for (int i = tid; i < N / 2; i += 1024)             // 16B vector staging
            ((uint4*)scand)[i] = ((const uint4*)gcand)[i];  // quiescent
        __syncthreads();
        for (int c = tid; c < N; c += 1024) {
            int l = cur[c];
            if (l == c) {
                u64 k = scand[c];
                if ((k >> 56) == tg) {                       // fresh this round
                    int v = (int)(k & 0xFFF);
                    int u = (int)((k >> 12) & 0xFFF);
                    int t = cur[v];
                    u64 tk = scand[t];
                    int mutual = 0;
                    if ((tk >> 56) == tg) {
                        int tv = (int)(tk & 0xFFF);
                        mutual = (cur[tv] == c);
                    }
                    if (mutual) {
                        if (c < t) {
                            if (bm == 0) { int idx = atomicAdd(&secnt, 1); ged[idx] = make_int2(u, v); }
                        } else l = t;
                    } else {
                        if (bm == 0) { int idx = atomicAdd(&secnt, 1); ged[idx] = make_int2(u, v); }
                        l = t;
                    }
                }
            }
            nxt[c] = (u16)l;
        }
        __syncthreads();
        int local = 0;
        for (int c = tid; c < N; c += 1024) {   // concurrent root-walk (monotone) + count
            int r = nxt[c];
            int n = nxt[r];
            while (n != r) { r = n; n = nxt[r]; }
            nxt[c] = (u16)r;
            local += (r == c) ? 1 : 0;
        }
        atomicAdd(&sdone[round], local);
        __syncthreads();
        done = (sdone[round] == 1);             // identical across blocks
        { u16* tmp = cur; cur = nxt; nxt = tmp; }
    }

    if (bm == 0) {
        // ============ Euler-tour rooting (leader block, depth-independent) =====
        u32* uvp  = (u32*)SM;                      // 16K @0 (comp buffers dead)
        u16* off  = (u16*)(SM + 16384);            // 8K
        u16* adj  = (u16*)(SM + 24576);            // 16K
        u16* succ = (u16*)(SM + 40960);            // 16K
        u16* rnk  = (u16*)(SM + 16384);            // aliases off+adj (dead)
        u32* minp = (u32*)(SM + 40960);            // aliases succ (dead)

        __syncthreads();
        const int ec = secnt;                      // == N-1
        for (int i = tid; i < ec; i += 1024) {
            int2 e = ged[i];
            uvp[i] = ((u32)e.x << 16) | (u32)e.y;
        }
        for (int i = tid; i < 2048; i += 1024) ((u32*)off)[i] = 0;
        __syncthreads();
        for (int i = tid; i < ec; i += 1024) {
            u32 w = uvp[i];
            int u = (int)(w >> 16), v = (int)(w & 0xFFFF);
            atomicAdd((u32*)off + (u >> 1), 1u << ((u & 1) * 16));
            atomicAdd((u32*)off + (v >> 1), 1u << ((v & 1) * 16));
        }
        __syncthreads();
        {
            const int i0 = tid * 4;
            int d0 = off[i0], d1 = off[i0 + 1], d2 = off[i0 + 2], d3 = off[i0 + 3];
            int t0 = d0, t01 = d0 + d1, t012 = t01 + d2, tot = t012 + d3;
            int inc = tot;
#pragma unroll
            for (int d = 1; d < 64; d <<= 1) {
                int o = __shfl_up(inc, d, 64);
                if (lane >= d) inc += o;
            }
            if (lane == 63) swar[wid] = inc;
            __syncthreads();
            if (wid == 0) {
                int v = (lane < 16) ? swar[lane] : 0;
                int vin = v;
#pragma unroll
                for (int d = 1; d < 16; d <<= 1) {
                    int o = __shfl_up(v, d, 64);
                    if (lane >= d) v += o;
                }
                if (lane < 16) swar[lane] = v - vin;
            }
            __syncthreads();
            int base = swar[wid] + (inc - tot);
            off[i0] = (u16)base;
            off[i0 + 1] = (u16)(base + t0);
            off[i0 + 2] = (u16)(base + t01);
            off[i0 + 3] = (u16)(base + t012);
        }
        __syncthreads();
        for (int e = tid; e < M2; e += 1024) {
            int i = e >> 1;
            u32 w = uvp[i];
            int src = (e & 1) ? (int)(w & 0xFFFF) : (int)(w >> 16);
            u32 old = atomicAdd((u32*)off + (src >> 1), 1u << ((src & 1) * 16));
            u32 slot = (old >> ((src & 1) * 16)) & 0xFFFFu;
            adj[slot] = (u16)e;
            succ[e] = (u16)slot;                 // temp: my slot
        }
        __syncthreads();
        const int e0 = adj[0];                   // first edge out of vertex 0 = tour start
        {
            u16 nsv[8];
            int k = 0;
            for (int e = tid; e < M2; e += 1024) {
                int i = e >> 1;
                u32 w = uvp[i];
                int v = (e & 1) ? (int)(w >> 16) : (int)(w & 0xFFFF);   // dst(e)
                int st = succ[e ^ 1];
                int start = (v == 0) ? 0 : off[v - 1];
                int end = off[v];
                int ns = (st + 1 < end) ? st + 1 : start;
                nsv[k++] = adj[ns];
            }
            __syncthreads();
            k = 0;
            for (int e = tid; e < M2; e += 1024) succ[e] = nsv[k++];
        }
        __syncthreads();
        for (int e = tid; e < M2; e += 1024) {
            u16 s = succ[e];
            if (s == (u16)e0) { succ[e] = (u16)e; rnk[e] = 0; }
            else rnk[e] = 1;
        }
        __syncthreads();
        for (int it = 0; it < 13; ++it) {
            u16 nr[8], s2[8];
            int k = 0;
            for (int e = tid; e < M2; e += 1024) {
                u16 s1 = succ[e];
                u16 r1 = rnk[e];
                nr[k] = (u16)(r1 + rnk[s1]);
                s2[k] = succ[s1];
                ++k;
            }
            __syncthreads();
            k = 0;
            for (int e = tid; e < M2; e += 1024) { rnk[e] = nr[k]; succ[e] = s2[k]; ++k; }
            __syncthreads();
        }
        for (int i = tid; i < N; i += 1024) minp[i] = 0xFFFFFFFFu;
        __syncthreads();
        for (int e = tid; e < M2; e += 1024) {
            int i = e >> 1;
            u32 w = uvp[i];
            int dst = (e & 1) ? (int)(w >> 16) : (int)(w & 0xFFFF);
            int srcv = (e & 1) ? (int)(w & 0xFFFF) : (int)(w >> 16);
            u32 p = (u32)(M2 - 1) - (u32)rnk[e];
            atomicMin(&minp[dst], (p << 16) | (u32)srcv);
        }
        __syncthreads();
        for (int v = tid; v < N; v += 1024) gpar[v] = (v == 0) ? 0 : (int)(minp[v] & 0xFFFFu);
    }

    // ---- global arrive; block 0 waits for all 128, then computes outputs ----
    __syncthreads();
    if (tid == 0) {
        __threadfence();
        atomicAdd(garr, 1);
    }
    if (b != 0) return;
    if (tid == 0) {
        while (__hip_atomic_load(garr, __ATOMIC_ACQUIRE, __HIP_MEMORY_SCOPE_AGENT) < 2 * MBLK)
            __builtin_amdgcn_s_sleep(1);
        __threadfence();
    }
    __syncthreads();

    // fused finalize (block 0 only)
    {
        float* rs12 = (float*)SM;            // tiny scratch
        float* rs21 = (float*)(SM + 64);
        int* rm = (int*)(SM + 128);
        const int* p1 = parent_g;
        const int* p2 = parent_g + N;
        float s12 = 0.f, s21 = 0.f;
        int mcnt = 0;
        for (int c = 1 + tid; c < N; c += 1024) {
            int a = p1[c];
            int bb = p2[c];
            float e1 = D1[(size_t)a * N + c] - D2[(size_t)a * N + c];
            float e2 = D2[(size_t)bb * N + c] - D1[(size_t)bb * N + c];
            s12 += e1 * e1;
            s21 += e2 * e2;
            mcnt += (a == bb) ? 1 : 0;
        }
#pragma unroll
        for (int off = 32; off > 0; off >>= 1) {
            s12 += __shfl_xor(s12, off, 64);
            s21 += __shfl_xor(s21, off, 64);
            mcnt += __shfl_xor(mcnt, off, 64);
        }
        if (lane == 0) { rs12[wid] = s12; rs21[wid] = s21; rm[wid] = mcnt; }
        __syncthreads();
        if (tid == 0) {
            float a = 0.f, bb = 0.f;
            int mm = 0;
#pragma unroll
            for (int w = 0; w < 16; ++w) { a += rs12[w]; bb += rs21[w]; mm += rm[w]; }
            float d12 = sqrtf(a);
            float d21 = sqrtf(bb);
            out[0] = d12 + d21;
            out[1] = d12;
            out[2] = d21;
            out[3] = (float)mm;
        }
    }
}

extern "C" void kernel_launch(void* const* d_in, const int* in_sizes, int n_in,
                              void* d_out, int out_size, void* d_ws, size_t ws_size,
                              hipStream_t stream) {
    const float* D1 = (const float*)d_in[0];
    const float* D2 = (const float*)d_in[1];

    int* parent = WS_PARENT(d_ws);
    int* rcnt = WS_RCNT(d_ws);
    float* rthr = WS_RTHR(d_ws);
    int2* edges = WS_EDGES(d_ws);
    u64* cand = WS_CAND(d_ws);
    int* meta = WS_META(d_ws);
    u64* lists = WS_LISTS(d_ws);

    build_kernel<<<2 * N, 256, 0, stream>>>(D1, D2, rcnt, rthr, lists, cand, meta);
    solve_kernel<<<2 * MBLK, 1024, 0, stream>>>(D1, D2, rcnt, rthr, lists, cand,
                                                edges, parent, meta, (float*)d_out);
}

// Round 10
// 258.081 us; speedup vs baseline: 1.0101x; 1.0101x over previous
//
#include <hip/hip_runtime.h>
#include <math.h>

#define N 4096
#define ROUNDS 12           // round 0 (folded) + 11: components at least halve per hook
#define INFKEY 0xFFFFFFFFFFFFFFFFULL
#define LCAP 64             // candidate-list capacity per row == wave width
#define EC (N - 1)          // MST edge count
#define M2 (2 * EC)         // directed edges (8190)
#define MBLK 32             // blocks per matrix (measured best: R8 @116us; 64 was 119, 128 was 244)
#define GSZ 8               // blocks per barrier group
#define NG (MBLK / GSZ)     // 4 groups per matrix
#define RPB (N / MBLK)      // 128 rows per block
#define RPW (RPB / 16)      // 8 rows per wave

typedef unsigned long long u64;
typedef unsigned int u32;
typedef unsigned short u16;
typedef unsigned char u8;

// ---- workspace layout (bytes) ----
#define WS_PARENT(ws) ((int*)((char*)(ws) + 0))          // int[2N]        32 KB
#define WS_RCNT(ws)   ((int*)((char*)(ws) + 32768))      // int[2N]        32 KB
#define WS_RTHR(ws)   ((float*)((char*)(ws) + 65536))    // float[2N]      32 KB
#define WS_EDGES(ws)  ((int2*)((char*)(ws) + 98304))     // int2[2N]       64 KB
#define WS_CAND(ws)   ((u64*)((char*)(ws) + 163840))     // u64[2][2N]    128 KB (double-buffered)
#define WS_META(ws)   ((int*)((char*)(ws) + 294912))     // int[64]
#define WS_LISTS(ws)  ((u64*)((char*)(ws) + 295168))     // u64[2N*LCAP]    4 MB, row-major

// cand key (TAGGED): ((ROUNDS-round) << 56) | (float_bits(w) << 24) | (u << 12) | v
//   Tags strictly decrease per round -> fresh keys always win atomicMin vs
//   stale same-buffer keys; phase C validates tag instead of INFKEY, so no
//   per-round buffer reset and only ONE mat_barrier per round.
// list entry: (float_bits(w) << 12) | j  (44 bits); order irrelevant.
// meta layout: matrix m uses meta[m*16+0..NG-1] = group arrival counters
//   (monotonic), meta[m*16+8] = global arrival counter (monotonic),
//   meta[m*16+9] = generation. meta[40] = final arrive counter (all blocks).

// Two-level monotonic spin barrier over MBLK blocks (verified R9). Group
// g = bm & (NG-1); group arrivals are mostly XCD-local L2 atomics; only NG
// group leaders touch the global counter. Monotonic targets -> no reset race.
__device__ __forceinline__ void mat_barrier(int* mbase, int bm, int target) {
    __syncthreads();
    if (threadIdx.x == 0) {
        __threadfence();
        const int g = bm & (NG - 1);
        int old = atomicAdd(&mbase[g], 1);            // group arrival (monotonic)
        bool released = false;
        if (old == target * GSZ - 1) {                // group leader this barrier
            int o2 = atomicAdd(&mbase[8], 1);         // global arrival
            if (o2 == target * NG - 1) {
                __hip_atomic_store(&mbase[9], target, __ATOMIC_RELEASE, __HIP_MEMORY_SCOPE_AGENT);
                released = true;
            }
        }
        if (!released) {
            while (__hip_atomic_load(&mbase[9], __ATOMIC_ACQUIRE, __HIP_MEMORY_SCOPE_AGENT) < target)
                __builtin_amdgcn_s_sleep(1);
        }
        __threadfence();
    }
    __syncthreads();
}

// One 256-thread BLOCK per row (grid 8192). sigma-based one-shot ball
// threshold: T = mean - 2.25*sigma targets ~50 entries (retry-halving if >64,
// P~2-3%); emission via LDS atomic counter (order irrelevant). Verified R8:
// deep lists cut solve's phase-B rescans, solve 155 -> 116 us.
__global__ __launch_bounds__(256) void build_kernel(const float* __restrict__ D1,
                                                    const float* __restrict__ D2,
                                                    int* __restrict__ rowcount,
                                                    float* __restrict__ rthresh,
                                                    u64* __restrict__ lists,
                                                    u64* __restrict__ cand,
                                                    int* __restrict__ meta) {
    const int gb = blockIdx.x;   // 8192 blocks: one per (matrix,row)
    const int tid = threadIdx.x;
    const int wid = tid >> 6, lane = tid & 63;

    // folded init: cand buffer 1 (buffer 0 is fully written below) + meta
    if (gb < 8) {
        int i = 2 * N + (gb * 256 + tid) * 4;
        cand[i] = INFKEY; cand[i + 1] = INFKEY; cand[i + 2] = INFKEY; cand[i + 3] = INFKEY;
    } else if (gb == 8 && tid < 64) {
        meta[tid] = 0;
    }

    const int m = gb >> 12;
    const int row = gb & (N - 1);
    const float* __restrict__ Drow = (m ? D2 : D1) + (size_t)row * N;

    __shared__ u64 skmin[4];
    __shared__ float ssum[4];
    __shared__ float ssq[4];
    __shared__ int semit;

    float4 v[4];
#pragma unroll
    for (int it = 0; it < 4; ++it)
        v[it] = *(const float4*)(Drow + it * 1024 + tid * 4);

    // pass 1: per-thread min KEY + sum over 16 elems
    u64 kmin = INFKEY;
    float sm = 0.f;
#pragma unroll
    for (int it = 0; it < 4; ++it) {
        float e4[4] = {v[it].x, v[it].y, v[it].z, v[it].w};
#pragma unroll
        for (int s = 0; s < 4; ++s) {
            float x = e4[s];
            if (x > 0.f) {   // excludes exact-zero diagonal
                u64 k = ((u64)__float_as_uint(x) << 12) | (unsigned)(it * 1024 + tid * 4 + s);
                if (k < kmin) kmin = k;
            }
            sm += x;         // self adds 0, harmless
        }
    }
#pragma unroll
    for (int off = 32; off > 0; off >>= 1) {
        u64 o = __shfl_xor(kmin, off, 64);
        if (o < kmin) kmin = o;
        sm += __shfl_xor(sm, off, 64);
    }
    if (lane == 0) { skmin[wid] = kmin; ssum[wid] = sm; }
    __syncthreads();
    kmin = skmin[0]; sm = ssum[0];
#pragma unroll
    for (int w = 1; w < 4; ++w) {
        if (skmin[w] < kmin) kmin = skmin[w];
        sm += ssum[w];
    }
    const float mn = __uint_as_float((u32)(kmin >> 12));
    const float mean = sm * (1.f / 4095.f);

    // pass 2 (registers): sum of squared deviations -> sigma
    float sq = 0.f;
#pragma unroll
    for (int it = 0; it < 4; ++it) {
        float e4[4] = {v[it].x, v[it].y, v[it].z, v[it].w};
#pragma unroll
        for (int s = 0; s < 4; ++s) {
            float x = e4[s];
            if (x > 0.f) { float d = x - mean; sq += d * d; }
        }
    }
#pragma unroll
    for (int off = 32; off > 0; off >>= 1) sq += __shfl_xor(sq, off, 64);
    if (lane == 0) ssq[wid] = sq;
    __syncthreads();
    sq = ssq[0] + ssq[1] + ssq[2] + ssq[3];
    const float sigma = sqrtf(fmaxf(sq * (1.f / 4095.f), 0.f));

    const float gap = mean - mn;
    float T = mean - 2.25f * sigma;          // ~1.2% quantile ~= 50 entries
    const float Tlo = mn + 0.001f * gap;     // guarantee at least the row min
    if (!(T > Tlo)) T = Tlo;                 // also catches NaN

    // emit-with-count loop: atomic positions, retry-halve on overflow (rare)
    u64* lp = lists + ((size_t)m * N + row) * LCAP;   // ROW-major
    int total = 0;
    for (int tries = 0; tries < 8; ++tries) {
        __syncthreads();
        if (tid == 0) semit = 0;
        __syncthreads();
#pragma unroll
        for (int it = 0; it < 4; ++it) {
            float e4[4] = {v[it].x, v[it].y, v[it].z, v[it].w};
#pragma unroll
            for (int s = 0; s < 4; ++s) {
                float x = e4[s];
                if (x > 0.f && x < T) {
                    int p = atomicAdd(&semit, 1);
                    if (p < LCAP)
                        lp[p] = ((u64)__float_as_uint(x) << 12) | (unsigned)(it * 1024 + tid * 4 + s);
                }
            }
        }
        __syncthreads();
        total = semit;                        // block-uniform
        if (total <= LCAP) break;             // uniform break
        T = mn + 0.5f * (T - mn);
    }

    if (tid == 0) {
        rowcount[m * N + row] = total;
        rthresh[m * N + row] = T;
        // Boruvka round-0 candidate, tag = ROUNDS, unique writer per row
        cand[m * N + row] = ((u64)ROUNDS << 56) | ((kmin >> 12) << 24) | ((u64)row << 12) | (kmin & 0xFFF);
    }
}

// 32 blocks per matrix (64 total) — measured best width. Round 0 = hook only.
// Rounds 1+: A (list scan + flush) -> B (bound filter + rare rescans) ->
// hierarchical mat_barrier -> C (redundant deterministic hook+compress).
// Width/barrier-count/phase-C levers all measured at +-3%: per-round cost is
// a latency floor (cross-XCD L2 + stragglers), not width- or sync-bound.
__global__ __launch_bounds__(1024) void solve_kernel(const float* __restrict__ D1,
                                                     const float* __restrict__ D2,
                                                     const int* __restrict__ rcnt,
                                                     const float* __restrict__ rthr,
                                                     const u64* __restrict__ lists,
                                                     u64* __restrict__ cand_g,
                                                     int2* __restrict__ edges_g,
                                                     int* __restrict__ parent_g,
                                                     int* __restrict__ meta,
                                                     float* __restrict__ out) {
    const int b = blockIdx.x;
    const int m = b / MBLK;
    const int bm = b - m * MBLK;
    const int tid = threadIdx.x;
    const int wid = tid >> 6, lane = tid & 63;
    const float* __restrict__ D = m ? D2 : D1;
    const int* __restrict__ grc = rcnt + m * N;
    const float* __restrict__ gth = rthr + m * N;
    const u64* __restrict__ gls = lists + (size_t)m * N * LCAP;
    int2* __restrict__ ged = edges_g + (size_t)m * N;
    int* __restrict__ gpar = parent_g + m * N;
    int* mbase = meta + m * 16;            // group counters [0..NG-1], global [8], gen [9]
    int* garr = meta + 40;                 // global arrive counter (all 64 blocks)
    const float INF = __builtin_inff();

    __shared__ __align__(16) char SM[57344];   // 56 KB arena, phase-aliased
    u16* comp0 = (u16*)SM;                     // 8 KB @0    (component buffer A)
    u16* comp1 = (u16*)(SM + 8192);            // 8 KB @8K   (component buffer B)
    u64* scand = (u64*)(SM + 16384);           // 32 KB @16K (local min mirror / staged cand)
    u16* sresc = (u16*)(SM + 49152);           // 8 KB  @48K (rescan list)
    __shared__ u8 sexh[RPB];                   // monotone exhausted-row flags
    __shared__ int snres, secnt, sdone[ROUNDS], swar[16];

    u16* cur = comp0;                          // swapped identically in all threads
    u16* nxt = comp1;

    for (int i = tid; i < N; i += 1024) cur[i] = (u16)i;
    for (int i = tid; i < RPB; i += 1024) sexh[i] = 0;
    if (tid == 0) secnt = 0;
    if (tid < ROUNDS) sdone[tid] = 0;
    int phase = 0;
    bool done = false;

    for (int round = 0; round < ROUNDS && !done; ++round) {
        const int buf = round & 1;
        const u64 tg = (u64)(ROUNDS - round);          // this round's tag
        const u64 tgs = tg << 56;
        u64* __restrict__ gcand = cand_g + (size_t)buf * 2 * N + m * N;

        if (round > 0) {
            for (int i = tid; i < N; i += 1024) scand[i] = INFKEY;
            if (tid == 0) snres = 0;
            __syncthreads();

            // ---- phase A: prefetched list scan; exhausted rows skip ----
            {
                const int lbase = wid * RPW;
                int cnts[RPW];
                u64 ent[RPW];
#pragma unroll
                for (int r = 0; r < RPW; ++r) {
                    int lrow = lbase + r;
                    cnts[r] = sexh[lrow] ? -1 : grc[bm * RPB + lrow];   // uniform scalar load
                }
#pragma unroll
                for (int r = 0; r < RPW; ++r) {   // independent global loads in flight
                    int lrow = lbase + r;
                    ent[r] = (cnts[r] > lane) ? gls[(size_t)(bm * RPB + lrow) * LCAP + lane]
                                              : INFKEY;
                }
#pragma unroll
                for (int r = 0; r < RPW; ++r) {
                    const int lrow = lbase + r;
                    const int row = bm * RPB + lrow;
                    if (cnts[r] < 0) {                       // known exhausted
                        if (lane == 0) { int i = atomicAdd(&snres, 1); sresc[i] = (u16)(row | 0x1000); }
                        continue;
                    }
                    if (cnts[r] > LCAP) {                    // defensive overflow
                        if (lane == 0) { int i = atomicAdd(&snres, 1); sresc[i] = (u16)(row | 0x4000); }
                        continue;
                    }
                    const int c = cur[row];
                    u64 e = ent[r];
                    u64 best = (e != INFKEY && cur[(int)(e & 0xFFF)] != c) ? e : INFKEY;
#pragma unroll
                    for (int off = 32; off > 0; off >>= 1) {
                        u64 o = __shfl_xor(best, off, 64);
                        if (o < best) best = o;
                    }
                    if (lane == 0) {
                        if (best != INFKEY) {
                            u64 key = tgs | ((best >> 12) << 24) | ((u64)row << 12) | (best & 0xFFF);
                            if (key < scand[c]) atomicMin(&scand[c], key);
                        } else {
                            sexh[lrow] = 1;                  // permanent (monotone)
                            int i = atomicAdd(&snres, 1); sresc[i] = (u16)(row | 0x1000);
                        }
                    }
                }
            }
            __syncthreads();
            for (int c = tid; c < N; c += 1024) {            // flush block-local mins
                u64 v = scand[c];
                if (v != INFKEY) atomicMin(&gcand[c], v);
            }
            __syncthreads();                 // own flushes visible to own filter reads

            // ---- phase B (no preceding barrier): bound filter; rare rescans ----
            for (int i = tid; i < snres; i += 1024) {
                u16 e = sresc[i];
                if (e & 0x1000) {
                    int row = e & 0xFFF;
                    int c = cur[row];
                    u64 cc = gcand[c];           // partial/monotone: skip stays safe
                    float w = ((cc >> 56) == tg) ? __uint_as_float((u32)(cc >> 24)) : INF;
                    if (!(gth[row] < w)) sresc[i] = 0xFFFF;
                }
            }
            __syncthreads();
            {
                const int nres = snres;
                for (int i = wid; i < nres; i += 16) {
                    u16 e = sresc[i];            // wave-uniform broadcast
                    if (e == 0xFFFF) continue;
                    int row = (int)(e & 0xFFF);
                    int c = cur[row];
                    const float* Drow = D + (size_t)row * N;
                    u64 best = INFKEY;
                    for (int j0 = lane * 4; j0 < N; j0 += 256) {
                        float4 d = *(const float4*)(Drow + j0);
                        ushort4 cj = *(const ushort4*)(cur + j0);
                        if (cj.x != c) { u64 k = ((u64)__float_as_uint(d.x) << 12) | (unsigned)(j0 + 0); if (k < best) best = k; }
                        if (cj.y != c) { u64 k = ((u64)__float_as_uint(d.y) << 12) | (unsigned)(j0 + 1); if (k < best) best = k; }
                        if (cj.z != c) { u64 k = ((u64)__float_as_uint(d.z) << 12) | (unsigned)(j0 + 2); if (k < best) best = k; }
                        if (cj.w != c) { u64 k = ((u64)__float_as_uint(d.w) << 12) | (unsigned)(j0 + 3); if (k < best) best = k; }
                    }
#pragma unroll
                    for (int off = 32; off > 0; off >>= 1) {
                        u64 o = __shfl_xor(best, off, 64);
                        if (o < best) best = o;
                    }
                    if (lane == 0 && best != INFKEY) {
                        u64 key = tgs | ((best >> 12) << 24) | ((u64)row << 12) | (best & 0xFFF);
                        atomicMin(&gcand[c], key);
                    }
                }
            }
            mat_barrier(mbase, bm, ++phase);   // the single per-round barrier
        }

        // ---- phase C (all blocks, redundant+deterministic): stage cand (tag-
        //      validated), hook into nxt, walk+count fused, swap buffers ----
        for (int i = tid; i < N / 2; i += 1024)             // 16B vector staging
            ((uint4*)scand)[i] = ((const uint4*)gcand)[i];  // quiescent
        __syncthreads();
        for (int c = tid; c < N; c += 1024) {
            int l = cur[c];
            if (l == c) {
                u64 k = scand[c];
                if ((k >> 56) == tg) {                       // fresh this round
                    int v = (int)(k & 0xFFF);
                    int u = (int)((k >> 12) & 0xFFF);
                    int t = cur[v];
                    u64 tk = scand[t];
                    int mutual = 0;
                    if ((tk >> 56) == tg) {
                        int tv = (int)(tk & 0xFFF);
                        mutual = (cur[tv] == c);
                    }
                    if (mutual) {
                        if (c < t) {
                            if (bm == 0) { int idx = atomicAdd(&secnt, 1); ged[idx] = make_int2(u, v); }
                        } else l = t;
                    } else {
                        if (bm == 0) { int idx = atomicAdd(&secnt, 1); ged[idx] = make_int2(u, v); }
                        l = t;
                    }
                }
            }
            nxt[c] = (u16)l;
        }
        __syncthreads();
        int local = 0;
        for (int c = tid; c < N; c += 1024) {   // concurrent root-walk (monotone) + count
            int r = nxt[c];
            int n = nxt[r];
            while (n != r) { r = n; n = nxt[r]; }
            nxt[c] = (u16)r;
            local += (r == c) ? 1 : 0;
        }
        atomicAdd(&sdone[round], local);
        __syncthreads();
        done = (sdone[round] == 1);             // identical across blocks
        { u16* tmp = cur; cur = nxt; nxt = tmp; }
    }

    if (bm == 0) {
        // ============ Euler-tour rooting (leader block, depth-independent) =====
        u32* uvp  = (u32*)SM;                      // 16K @0 (comp buffers dead)
        u16* off  = (u16*)(SM + 16384);            // 8K
        u16* adj  = (u16*)(SM + 24576);            // 16K
        u16* succ = (u16*)(SM + 40960);            // 16K
        u16* rnk  = (u16*)(SM + 16384);            // aliases off+adj (dead)
        u32* minp = (u32*)(SM + 40960);            // aliases succ (dead)

        __syncthreads();
        const int ec = secnt;                      // == N-1
        for (int i = tid; i < ec; i += 1024) {
            int2 e = ged[i];
            uvp[i] = ((u32)e.x << 16) | (u32)e.y;
        }
        for (int i = tid; i < 2048; i += 1024) ((u32*)off)[i] = 0;
        __syncthreads();
        for (int i = tid; i < ec; i += 1024) {
            u32 w = uvp[i];
            int u = (int)(w >> 16), v = (int)(w & 0xFFFF);
            atomicAdd((u32*)off + (u >> 1), 1u << ((u & 1) * 16));
            atomicAdd((u32*)off + (v >> 1), 1u << ((v & 1) * 16));
        }
        __syncthreads();
        {
            const int i0 = tid * 4;
            int d0 = off[i0], d1 = off[i0 + 1], d2 = off[i0 + 2], d3 = off[i0 + 3];
            int t0 = d0, t01 = d0 + d1, t012 = t01 + d2, tot = t012 + d3;
            int inc = tot;
#pragma unroll
            for (int d = 1; d < 64; d <<= 1) {
                int o = __shfl_up(inc, d, 64);
                if (lane >= d) inc += o;
            }
            if (lane == 63) swar[wid] = inc;
            __syncthreads();
            if (wid == 0) {
                int v = (lane < 16) ? swar[lane] : 0;
                int vin = v;
#pragma unroll
                for (int d = 1; d < 16; d <<= 1) {
                    int o = __shfl_up(v, d, 64);
                    if (lane >= d) v += o;
                }
                if (lane < 16) swar[lane] = v - vin;
            }
            __syncthreads();
            int base = swar[wid] + (inc - tot);
            off[i0] = (u16)base;
            off[i0 + 1] = (u16)(base + t0);
            off[i0 + 2] = (u16)(base + t01);
            off[i0 + 3] = (u16)(base + t012);
        }
        __syncthreads();
        for (int e = tid; e < M2; e += 1024) {
            int i = e >> 1;
            u32 w = uvp[i];
            int src = (e & 1) ? (int)(w & 0xFFFF) : (int)(w >> 16);
            u32 old = atomicAdd((u32*)off + (src >> 1), 1u << ((src & 1) * 16));
            u32 slot = (old >> ((src & 1) * 16)) & 0xFFFFu;
            adj[slot] = (u16)e;
            succ[e] = (u16)slot;                 // temp: my slot
        }
        __syncthreads();
        const int e0 = adj[0];                   // first edge out of vertex 0 = tour start
        {
            u16 nsv[8];
            int k = 0;
            for (int e = tid; e < M2; e += 1024) {
                int i = e >> 1;
                u32 w = uvp[i];
                int v = (e & 1) ? (int)(w >> 16) : (int)(w & 0xFFFF);   // dst(e)
                int st = succ[e ^ 1];
                int start = (v == 0) ? 0 : off[v - 1];
                int end = off[v];
                int ns = (st + 1 < end) ? st + 1 : start;
                nsv[k++] = adj[ns];
            }
            __syncthreads();
            k = 0;
            for (int e = tid; e < M2; e += 1024) succ[e] = nsv[k++];
        }
        __syncthreads();
        for (int e = tid; e < M2; e += 1024) {
            u16 s = succ[e];
            if (s == (u16)e0) { succ[e] = (u16)e; rnk[e] = 0; }
            else rnk[e] = 1;
        }
        __syncthreads();
        for (int it = 0; it < 13; ++it) {
            u16 nr[8], s2[8];
            int k = 0;
            for (int e = tid; e < M2; e += 1024) {
                u16 s1 = succ[e];
                u16 r1 = rnk[e];
                nr[k] = (u16)(r1 + rnk[s1]);
                s2[k] = succ[s1];
                ++k;
            }
            __syncthreads();
            k = 0;
            for (int e = tid; e < M2; e += 1024) { rnk[e] = nr[k]; succ[e] = s2[k]; ++k; }
            __syncthreads();
        }
        for (int i = tid; i < N; i += 1024) minp[i] = 0xFFFFFFFFu;
        __syncthreads();
        for (int e = tid; e < M2; e += 1024) {
            int i = e >> 1;
            u32 w = uvp[i];
            int dst = (e & 1) ? (int)(w >> 16) : (int)(w & 0xFFFF);
            int srcv = (e & 1) ? (int)(w & 0xFFFF) : (int)(w >> 16);
            u32 p = (u32)(M2 - 1) - (u32)rnk[e];
            atomicMin(&minp[dst], (p << 16) | (u32)srcv);
        }
        __syncthreads();
        for (int v = tid; v < N; v += 1024) gpar[v] = (v == 0) ? 0 : (int)(minp[v] & 0xFFFFu);
    }

    // ---- global arrive; block 0 waits for all 64, then computes outputs ----
    __syncthreads();
    if (tid == 0) {
        __threadfence();
        atomicAdd(garr, 1);
    }
    if (b != 0) return;
    if (tid == 0) {
        while (__hip_atomic_load(garr, __ATOMIC_ACQUIRE, __HIP_MEMORY_SCOPE_AGENT) < 2 * MBLK)
            __builtin_amdgcn_s_sleep(1);
        __threadfence();
    }
    __syncthreads();

    // fused finalize (block 0 only)
    {
        float* rs12 = (float*)SM;            // tiny scratch
        float* rs21 = (float*)(SM + 64);
        int* rm = (int*)(SM + 128);
        const int* p1 = parent_g;
        const int* p2 = parent_g + N;
        float s12 = 0.f, s21 = 0.f;
        int mcnt = 0;
        for (int c = 1 + tid; c < N; c += 1024) {
            int a = p1[c];
            int bb = p2[c];
            float e1 = D1[(size_t)a * N + c] - D2[(size_t)a * N + c];
            float e2 = D2[(size_t)bb * N + c] - D1[(size_t)bb * N + c];
            s12 += e1 * e1;
            s21 += e2 * e2;
            mcnt += (a == bb) ? 1 : 0;
        }
#pragma unroll
        for (int off = 32; off > 0; off >>= 1) {
            s12 += __shfl_xor(s12, off, 64);
            s21 += __shfl_xor(s21, off, 64);
            mcnt += __shfl_xor(mcnt, off, 64);
        }
        if (lane == 0) { rs12[wid] = s12; rs21[wid] = s21; rm[wid] = mcnt; }
        __syncthreads();
        if (tid == 0) {
            float a = 0.f, bb = 0.f;
            int mm = 0;
#pragma unroll
            for (int w = 0; w < 16; ++w) { a += rs12[w]; bb += rs21[w]; mm += rm[w]; }
            float d12 = sqrtf(a);
            float d21 = sqrtf(bb);
            out[0] = d12 + d21;
            out[1] = d12;
            out[2] = d21;
            out[3] = (float)mm;
        }
    }
}

extern "C" void kernel_launch(void* const* d_in, const int* in_sizes, int n_in,
                              void* d_out, int out_size, void* d_ws, size_t ws_size,
                              hipStream_t stream) {
    const float* D1 = (const float*)d_in[0];
    const float* D2 = (const float*)d_in[1];

    int* parent = WS_PARENT(d_ws);
    int* rcnt = WS_RCNT(d_ws);
    float* rthr = WS_RTHR(d_ws);
    int2* edges = WS_EDGES(d_ws);
    u64* cand = WS_CAND(d_ws);
    int* meta = WS_META(d_ws);
    u64* lists = WS_LISTS(d_ws);

    build_kernel<<<2 * N, 256, 0, stream>>>(D1, D2, rcnt, rthr, lists, cand, meta);
    solve_kernel<<<2 * MBLK, 1024, 0, stream>>>(D1, D2, rcnt, rthr, lists, cand,
                                                edges, parent, meta, (float*)d_out);
}